// Round 13
// baseline (589.839 us; speedup 1.0000x reference)
//
#include <hip/hip_runtime.h>
#include <hip/hip_fp16.h>

#define N_NODES 100000
#define E_EDGES 1600000
#define F 256              // feature width at every stage
#define LV_OFF 12800000    // 100000*128
#define NBUK 782           // ceil(100000/128) dst-buckets of 128 nodes (CSR build)
#define EPB 8192           // edges per binning block
#define NBLK_BIN 196       // ceil(1.6M/8192)
#define NTILE64 1563       // ceil(100000/64) agg+gemm tiles

typedef _Float16 half8 __attribute__((ext_vector_type(8)));
typedef _Float16 f16x4 __attribute__((ext_vector_type(4)));
typedef float    f32x4 __attribute__((ext_vector_type(4)));
typedef unsigned u32x4 __attribute__((ext_vector_type(4)));

// fp16-pair (packed in u32) fused into two fp32 accumulators via v_fma_mix_f32.
__device__ __forceinline__ void fmix2(float& lo, float& hi, unsigned v) {
    asm("v_fma_mix_f32 %0, %2, 1.0, %0 op_sel_hi:[1,0,0]\n\t"
        "v_fma_mix_f32 %1, %2, 1.0, %1 op_sel:[1,0,0] op_sel_hi:[1,0,0]"
        : "+v"(lo), "+v"(hi) : "v"(v));
}

__device__ __forceinline__ void acc_row(float* a, half8 v) {
    u32x4 u = __builtin_bit_cast(u32x4, v);
    fmix2(a[0], a[1], u[0]);
    fmix2(a[2], a[3], u[1]);
    fmix2(a[4], a[5], u[2]);
    fmix2(a[6], a[7], u[3]);
}

// ---------------- fused prep: wprep (256 blocks) + binA-with-count (196 blocks) ----------------
__global__ __launch_bounds__(256) void k_prep(
    const float* __restrict__ W1, const float* __restrict__ Wmu, const float* __restrict__ Wlv,
    _Float16* __restrict__ Wt1, _Float16* __restrict__ Wtc,
    const int* __restrict__ dst, int* __restrict__ gcnt, int* __restrict__ cbase,
    int* __restrict__ cnt)
{
    __shared__ int h[NBUK];
    int bid = blockIdx.x, tid = threadIdx.x;
    if (bid < 256) {
        int idx = bid * 256 + tid;   // 65536
        int n = idx >> 8, k = idx & 255;
        Wt1[n * 256 + k] = (_Float16)W1[k * 256 + n];
        float wc = (n < 128) ? Wmu[k * 128 + n] : Wlv[k * 128 + (n - 128)];
        Wtc[n * 256 + k] = (_Float16)wc;
        return;
    }
    int blk = bid - 256;             // 0..195
    for (int b = tid; b < NBUK; b += 256) h[b] = 0;
    __syncthreads();
    int e0 = blk * EPB, e1 = min(e0 + EPB, E_EDGES);
    for (int e = e0 + tid; e < e1; e += 256) {
        int d = dst[e];
        atomicAdd(&h[d >> 7], 1);    // bucket histogram (LDS)
        atomicAdd(&cnt[d], 1);       // per-node degree (global)
    }
    __syncthreads();
    for (int b = tid; b < NBUK; b += 256) {
        int c = h[b];
        cbase[blk * NBUK + b] = c ? atomicAdd(&gcnt[b], c) : 0;
    }
}

// ---------------- fused: bucket scan (block 0) + dis (blocks 1..98) ----------------
__global__ __launch_bounds__(1024) void k_scan_dis(const int* __restrict__ gcnt,
                                                   int* __restrict__ gbase,
                                                   const int* __restrict__ cnt,
                                                   float* __restrict__ dis) {
    int tid = threadIdx.x;
    if (blockIdx.x != 0) {
        int i = (blockIdx.x - 1) * 1024 + tid;
        if (i < N_NODES) dis[i] = rsqrtf((float)cnt[i] + 1.0f);
        return;
    }
    __shared__ int sd[1024];
    int v = (tid < NBUK) ? gcnt[tid] : 0;
    sd[tid] = v;
    __syncthreads();
    for (int off = 1; off < 1024; off <<= 1) {
        int t = (tid >= off) ? sd[tid - off] : 0;
        __syncthreads();
        sd[tid] += t;
        __syncthreads();
    }
    if (tid < NBUK) gbase[tid] = sd[tid] - v;    // exclusive
    if (tid == NBUK - 1) gbase[NBUK] = sd[tid];  // total = E
}

// ---------------- binning pass D: per-bucket group-by-dst -> csr_src, row_off ----------------
__global__ __launch_bounds__(256) void k_binD(const unsigned long long* __restrict__ ebuf,
                                              const int* __restrict__ gbase,
                                              int* __restrict__ csr_src, int* __restrict__ row_off) {
    __shared__ int dh[128], dsc[128], dcur[128];
    int b = blockIdx.x, tid = threadIdx.x;
    if (tid < 128) dh[tid] = 0;
    __syncthreads();
    int s0 = gbase[b], s1 = gbase[b + 1];
    for (int i = s0 + tid; i < s1; i += 256)
        atomicAdd(&dh[(int)(ebuf[i] >> 32) & 127], 1);
    __syncthreads();
    if (tid < 128) dsc[tid] = dh[tid];
    __syncthreads();
    for (int off = 1; off < 128; off <<= 1) {
        int t = 0;
        if (tid < 128 && tid >= off) t = dsc[tid - off];
        __syncthreads();
        if (tid < 128) dsc[tid] += t;
        __syncthreads();
    }
    if (tid < 128) {
        int ex = dsc[tid] - dh[tid];   // exclusive within bucket
        dcur[tid] = ex;
        int node = b * 128 + tid;
        if (node < N_NODES) row_off[node] = s0 + ex;
    }
    if (b == 0 && tid == 128) row_off[N_NODES] = E_EDGES;
    __syncthreads();
    for (int i = s0 + tid; i < s1; i += 256) {
        unsigned long long ed = ebuf[i];
        int dl = (int)(ed >> 32) & 127;
        int lr = atomicAdd(&dcur[dl], 1);
        csr_src[s0 + lr] = (int)(ed & 0xFFFFFFFFull);
    }
}

// ---------------- fp16 MFMA GEMM tile body, 8 waves, 64x64 per wave, epilogue *dis[m] ----------------
__device__ __forceinline__ void gemm_tile_f32(
    const float* __restrict__ A, const _Float16* __restrict__ Bt,
    const float* __restrict__ dis, _Float16* __restrict__ G, int M,
    int m0, int tid, _Float16* Ah, _Float16* Bh)
{
    const int wave = tid >> 6, lane = tid & 63;
    const int wm   = wave & 1, wn = wave >> 1;      // 64-row half, 64-col quarter
    const int lrow = lane & 15, kgrp = lane >> 4;

    f32x4 acc[4][4];
#pragma unroll
    for (int i = 0; i < 4; i++)
#pragma unroll
        for (int j = 0; j < 4; j++) acc[i][j] = (f32x4){0.f, 0.f, 0.f, 0.f};

    for (int kt = 0; kt < 256; kt += 64) {
        // ---- stage A (512 threads) ----
#pragma unroll
        for (int p = 0; p < 4; ++p) {
            int u = p * 512 + tid;        // 2048 float4
            int row = u >> 4, kq = u & 15;
            int gm = m0 + row; if (gm >= M) gm = M - 1;
            f32x4 v = __builtin_nontemporal_load(
                reinterpret_cast<const f32x4*>(A + (size_t)gm * F + kt + kq * 4));
            f16x4 h4;
            h4[0] = (_Float16)v[0]; h4[1] = (_Float16)v[1];
            h4[2] = (_Float16)v[2]; h4[3] = (_Float16)v[3];
            *reinterpret_cast<f16x4*>(&Ah[row * 64 + ((kq * 4) ^ ((row & 7) << 3))]) = h4;
        }
        // ---- stage B ----
#pragma unroll
        for (int p = 0; p < 4; ++p) {
            int u = p * 512 + tid;            // 2048 half8
            int n = u >> 3, slot = u & 7;
            half8 v = *reinterpret_cast<const half8*>(Bt + (size_t)n * F + kt + slot * 8);
            *reinterpret_cast<half8*>(&Bh[n * 64 + ((slot * 8) ^ ((n & 7) << 3))]) = v;
        }
        __syncthreads();
#pragma unroll
        for (int ks = 0; ks < 2; ++ks) {
            int kk = ks * 32 + kgrp * 8;
            half8 ah[4];
#pragma unroll
            for (int i = 0; i < 4; ++i) {
                int row = wm * 64 + i * 16 + lrow;
                ah[i] = *reinterpret_cast<const half8*>(&Ah[row * 64 + (kk ^ ((row & 7) << 3))]);
            }
#pragma unroll
            for (int j = 0; j < 4; ++j) {
                int col = wn * 64 + j * 16 + lrow;
                half8 bh = *reinterpret_cast<const half8*>(&Bh[col * 64 + (kk ^ ((col & 7) << 3))]);
#pragma unroll
                for (int i = 0; i < 4; ++i)
                    acc[i][j] = __builtin_amdgcn_mfma_f32_16x16x32_f16(ah[i], bh, acc[i][j], 0, 0, 0);
            }
        }
        __syncthreads();
    }

#pragma unroll
    for (int i = 0; i < 4; ++i) {
#pragma unroll
        for (int r = 0; r < 4; ++r) {
            int m = m0 + wm * 64 + i * 16 + kgrp * 4 + r;
            if (m >= M) continue;
            float dv = dis[m];
#pragma unroll
            for (int j = 0; j < 4; ++j) {
                int n = wn * 64 + j * 16 + lrow;
                G[(size_t)m * F + n] = (_Float16)(acc[i][j][r] * dv);
            }
        }
    }
}

// ---------------- fused: GEMM-1 (782 tiles) + binC (196 blocks), interleaved 4:1 ----------------
__global__ __launch_bounds__(512, 6) void k_gemm_binC(
    const float* __restrict__ A, const _Float16* __restrict__ Bt,
    const float* __restrict__ dis, _Float16* __restrict__ G, int M,
    const int* __restrict__ src, const int* __restrict__ dst,
    const int* __restrict__ gbase, const int* __restrict__ cbase,
    unsigned long long* __restrict__ ebuf)
{
    __shared__ _Float16 smem[128 * 64 + 256 * 64];   // 48 KB, reused by both roles
    int bid = blockIdx.x, tid = threadIdx.x;
    int r5 = bid % 5;
    if (r5 < 4) {
        int gid = (bid / 5) * 4 + r5;
        if (gid < 782)
            gemm_tile_f32(A, Bt, dis, G, M, gid * 128, tid, smem, smem + 128 * 64);
        return;
    }
    // ---- binC role ----
    int* h2 = (int*)smem;          // [NBUK]
    int* bs = h2 + NBUK;           // [NBUK]
    int blk = bid / 5;             // 0..195
    for (int b = tid; b < NBUK; b += 512) {
        h2[b] = 0;
        bs[b] = gbase[b] + cbase[blk * NBUK + b];
    }
    __syncthreads();
    int e0 = blk * EPB, e1 = min(e0 + EPB, E_EDGES);
    for (int e = e0 + tid; e < e1; e += 512) {
        int d = dst[e];
        int b = d >> 7;
        int lr = atomicAdd(&h2[b], 1);
        ebuf[bs[b] + lr] = ((unsigned long long)(unsigned)d << 32) | (unsigned)src[e];
    }
}

// ---------------- fused layer boundary, 64-row tile: aggregate(g1)->LDS h -> GEMM -> g2 ----------------
// LDS 48 KB -> 3 blocks/CU (24 gather-waves/CU). h never touches HBM.
__global__ __launch_bounds__(512, 6) void k_agg_gemm(
    const _Float16* __restrict__ g1, const int* __restrict__ row_off,
    const int* __restrict__ csr_src, const float* __restrict__ dis,
    const float* __restrict__ b1, const _Float16* __restrict__ Bt,
    _Float16* __restrict__ G2, int M)
{
    __shared__ _Float16 HT[64 * 256];    // 32 KB h-tile, row-swizzled
    __shared__ _Float16 Bs[256 * 32];    // 16 KB B chunk
    const int tid  = threadIdx.x;
    const int m0   = blockIdx.x * 64;
    const int wave = tid >> 6, lane = tid & 63;
    const int hf   = lane >> 5, lp = lane & 31;
    const half8* g8 = reinterpret_cast<const half8*>(g1);

    // ---- phase 1: aggregate 8 rows per wave ----
    for (int it = 0; it < 8; ++it) {
        int r  = wave * 8 + it;
        int gr = m0 + r;
        float a0[8] = {0,0,0,0,0,0,0,0}, a1[8] = {0,0,0,0,0,0,0,0};
        if (gr < M) {
            if (hf == 0) {
                half8 sv = g8[(size_t)gr * 32 + lp];   // self-loop (g1 already dis-scaled)
#pragma unroll
                for (int k = 0; k < 8; k++) a0[k] = (float)sv[k];
            }
            int j0 = row_off[gr], j1 = row_off[gr + 1];
            int j = j0 + hf;
            for (; j + 10 < j1; j += 12) {
                int s0 = csr_src[j],     s1 = csr_src[j + 2], s2 = csr_src[j + 4];
                int s3 = csr_src[j + 6], s4 = csr_src[j + 8], s5 = csr_src[j + 10];
                half8 v0 = g8[(size_t)s0 * 32 + lp];
                half8 v1 = g8[(size_t)s1 * 32 + lp];
                half8 v2 = g8[(size_t)s2 * 32 + lp];
                half8 v3 = g8[(size_t)s3 * 32 + lp];
                half8 v4 = g8[(size_t)s4 * 32 + lp];
                half8 v5 = g8[(size_t)s5 * 32 + lp];
                acc_row(a0, v0); acc_row(a1, v1);
                acc_row(a0, v2); acc_row(a1, v3);
                acc_row(a0, v4); acc_row(a1, v5);
            }
            for (; j + 2 < j1; j += 4) {
                int sA = csr_src[j], sB = csr_src[j + 2];
                half8 vA = g8[(size_t)sA * 32 + lp];
                half8 vB = g8[(size_t)sB * 32 + lp];
                acc_row(a0, vA); acc_row(a1, vB);
            }
            if (j < j1) {
                int sA = csr_src[j];
                half8 vA = g8[(size_t)sA * 32 + lp];
                acc_row(a0, vA);
            }
        }
#pragma unroll
        for (int k = 0; k < 8; k++) {
            a0[k] += a1[k];
            a0[k] += __shfl_xor(a0[k], 32);
        }
        int c = lp * 8 + hf * 4;
        f16x4 o = (f16x4){(_Float16)0, (_Float16)0, (_Float16)0, (_Float16)0};
        if (gr < M) {
            float dd = dis[gr];
            float4 bb = *reinterpret_cast<const float4*>(b1 + c);
            o[0] = (_Float16)fmaxf(fmaf(dd, a0[hf * 4 + 0], bb.x), 0.0f);
            o[1] = (_Float16)fmaxf(fmaf(dd, a0[hf * 4 + 1], bb.y), 0.0f);
            o[2] = (_Float16)fmaxf(fmaf(dd, a0[hf * 4 + 2], bb.z), 0.0f);
            o[3] = (_Float16)fmaxf(fmaf(dd, a0[hf * 4 + 3], bb.w), 0.0f);
        }
        *reinterpret_cast<f16x4*>(&HT[r * 256 + (c ^ ((r & 7) << 3))]) = o;
    }
    __syncthreads();

    // ---- phase 2: 64x256 GEMM from LDS h-tile; wave = 32-col slice ----
    const int wn = wave;                       // 0..7
    const int lrow = lane & 15, kgrp = lane >> 4;
    f32x4 acc[4][2];
#pragma unroll
    for (int i = 0; i < 4; i++)
#pragma unroll
        for (int j = 0; j < 2; j++) acc[i][j] = (f32x4){0.f, 0.f, 0.f, 0.f};

    for (int kt = 0; kt < 256; kt += 32) {
#pragma unroll
        for (int p = 0; p < 2; ++p) {
            int u = p * 512 + tid;        // 1024 half8
            int n = u >> 2, slot = u & 3;
            half8 v = *reinterpret_cast<const half8*>(Bt + (size_t)n * F + kt + slot * 8);
            *reinterpret_cast<half8*>(&Bs[n * 32 + ((slot * 8) ^ ((n & 3) << 3))]) = v;
        }
        __syncthreads();
        int kk = kgrp * 8;
        half8 ah[4];
#pragma unroll
        for (int i = 0; i < 4; ++i) {
            int row = i * 16 + lrow;
            ah[i] = *reinterpret_cast<const half8*>(&HT[row * 256 + ((kt + kk) ^ ((row & 7) << 3))]);
        }
#pragma unroll
        for (int j = 0; j < 2; ++j) {
            int col = wn * 32 + j * 16 + lrow;
            half8 bh = *reinterpret_cast<const half8*>(&Bs[col * 32 + (kk ^ ((col & 3) << 3))]);
#pragma unroll
            for (int i = 0; i < 4; ++i)
                acc[i][j] = __builtin_amdgcn_mfma_f32_16x16x32_f16(ah[i], bh, acc[i][j], 0, 0, 0);
        }
        __syncthreads();
    }

    // ---- epilogue: scale by dis[m], write g2 ----
#pragma unroll
    for (int i = 0; i < 4; ++i) {
#pragma unroll
        for (int r = 0; r < 4; ++r) {
            int m = m0 + i * 16 + kgrp * 4 + r;
            if (m >= M) continue;
            float dv = dis[m];
#pragma unroll
            for (int j = 0; j < 2; ++j) {
                int n = wn * 32 + j * 16 + lrow;
                G2[(size_t)m * F + n] = (_Float16)(acc[i][j][r] * dv);
            }
        }
    }
}

// ---------------- CSR gather layer-2 epilogue (mu | logvar split) ----------------
__global__ __launch_bounds__(256) void k_aggregate_out(
    const _Float16* __restrict__ g, const int* __restrict__ row_off,
    const int* __restrict__ csr_src, const float* __restrict__ dis,
    const float* __restrict__ bmu, const float* __restrict__ blv,
    float* __restrict__ out)
{
    int d = blockIdx.x * 4 + (threadIdx.x >> 6);
    int lane = threadIdx.x & 63;
    int hf = lane >> 5, lp = lane & 31;
    const half8* g8 = reinterpret_cast<const half8*>(g);   // 32 half8 per row
    float a0[8] = {0,0,0,0,0,0,0,0}, a1[8] = {0,0,0,0,0,0,0,0};
    if (hf == 0) {
        half8 sv = g8[(size_t)d * 32 + lp];   // self-loop (g already dis-scaled)
#pragma unroll
        for (int k = 0; k < 8; k++) a0[k] = (float)sv[k];
    }
    int j0 = row_off[d], j1 = row_off[d + 1];
    int j = j0 + hf;
    for (; j + 10 < j1; j += 12) {
        int s0 = csr_src[j],     s1 = csr_src[j + 2], s2 = csr_src[j + 4];
        int s3 = csr_src[j + 6], s4 = csr_src[j + 8], s5 = csr_src[j + 10];
        half8 v0 = g8[(size_t)s0 * 32 + lp];
        half8 v1 = g8[(size_t)s1 * 32 + lp];
        half8 v2 = g8[(size_t)s2 * 32 + lp];
        half8 v3 = g8[(size_t)s3 * 32 + lp];
        half8 v4 = g8[(size_t)s4 * 32 + lp];
        half8 v5 = g8[(size_t)s5 * 32 + lp];
        acc_row(a0, v0); acc_row(a1, v1);
        acc_row(a0, v2); acc_row(a1, v3);
        acc_row(a0, v4); acc_row(a1, v5);
    }
    for (; j + 2 < j1; j += 4) {
        int sA = csr_src[j], sB = csr_src[j + 2];
        half8 vA = g8[(size_t)sA * 32 + lp];
        half8 vB = g8[(size_t)sB * 32 + lp];
        acc_row(a0, vA); acc_row(a1, vB);
    }
    if (j < j1) {
        int sA = csr_src[j];
        half8 vA = g8[(size_t)sA * 32 + lp];
        acc_row(a0, vA);
    }
#pragma unroll
    for (int k = 0; k < 8; k++) {
        a0[k] += a1[k];
        a0[k] += __shfl_xor(a0[k], 32);
    }
    float dd = dis[d];
    int ch = lp * 8 + hf * 4;                 // 0..252
    float va = a0[hf * 4 + 0], vb = a0[hf * 4 + 1], vc = a0[hf * 4 + 2], vd = a0[hf * 4 + 3];
    if (ch < 128) {
        float4 bb = *reinterpret_cast<const float4*>(bmu + ch);
        f32x4 o = {fmaf(dd, va, bb.x), fmaf(dd, vb, bb.y),
                   fmaf(dd, vc, bb.z), fmaf(dd, vd, bb.w)};
        __builtin_nontemporal_store(o, reinterpret_cast<f32x4*>(out + (size_t)d * 128 + ch));
    } else {
        int c2 = ch - 128;
        float4 bb = *reinterpret_cast<const float4*>(blv + c2);
        f32x4 o = {fmaf(dd, va, bb.x), fmaf(dd, vb, bb.y),
                   fmaf(dd, vc, bb.z), fmaf(dd, vd, bb.w)};
        __builtin_nontemporal_store(o, reinterpret_cast<f32x4*>(out + LV_OFF + (size_t)d * 128 + c2));
    }
}

extern "C" void kernel_launch(void* const* d_in, const int* in_sizes, int n_in,
                              void* d_out, int out_size, void* d_ws, size_t ws_size,
                              hipStream_t stream) {
    const float* x   = (const float*)d_in[0];
    const int*   ei  = (const int*)d_in[1];
    const int*   src = ei;
    const int*   dst = ei + E_EDGES;
    const float* W1  = (const float*)d_in[2];
    const float* b1  = (const float*)d_in[3];
    const float* Wmu = (const float*)d_in[4];
    const float* bmu = (const float*)d_in[5];
    const float* Wlv = (const float*)d_in[6];
    const float* blv = (const float*)d_in[7];
    float* out = (float*)d_out;

    // workspace carve-up (1 KiB aligned)
    char* ws = (char*)d_ws;
    size_t o = 0;
    auto carve = [&](size_t bytes) -> char* {
        char* p = ws + o;
        o = (o + bytes + 1023) & ~(size_t)1023;
        return p;
    };
    float*    dis     = (float*)   carve(400000);
    int*      cnt     = (int*)     carve(400000);
    int*      row_off = (int*)     carve(400004);
    int*      gcnt    = (int*)     carve(NBUK * 4);
    int*      gbase   = (int*)     carve((NBUK + 1) * 4);
    int*      cbase   = (int*)     carve((size_t)NBLK_BIN * NBUK * 4);   // 613 KB
    _Float16* Wt1     = (_Float16*)carve(131072);
    _Float16* Wtc     = (_Float16*)carve(131072);
    int*      csr_src = (int*)     carve((size_t)E_EDGES * 4);           // 6.4 MB
    unsigned long long* ebuf = (unsigned long long*)carve((size_t)E_EDGES * 8);  // 12.8 MB
    _Float16* g1      = (_Float16*)carve((size_t)N_NODES * F * 2);       // 51.2 MB
    _Float16* g2      = (_Float16*)carve((size_t)N_NODES * F * 2);       // 51.2 MB
    (void)ws_size;

    // ---- pipeline ----
    hipMemsetAsync(cnt, 0, 400000, stream);
    hipMemsetAsync(gcnt, 0, NBUK * 4, stream);
    k_prep    <<<256 + NBLK_BIN, 256, 0, stream>>>(W1, Wmu, Wlv, Wt1, Wtc, dst, gcnt, cbase, cnt);
    k_scan_dis<<<99, 1024, 0, stream>>>(gcnt, gbase, cnt, dis);
    // layer-1 GEMM (dis epilogue) fused with binC
    k_gemm_binC<<<980, 512, 0, stream>>>(x, Wt1, dis, g1, N_NODES, src, dst, gbase, cbase, ebuf);
    k_binD     <<<NBUK, 256, 0, stream>>>(ebuf, gbase, csr_src, row_off);

    // fused: aggregate layer-1 (h in LDS only, 64-row tiles) + layer-2 GEMM -> g2
    k_agg_gemm<<<NTILE64, 512, 0, stream>>>(g1, row_off, csr_src, dis, b1, Wtc, g2, N_NODES);

    // layer-2 aggregate: out = dis*(g2[self]+sum g2[nbr]) + b (mu | logvar)
    k_aggregate_out<<<N_NODES / 4, 256, 0, stream>>>(g2, row_off, csr_src, dis, bmu, blv, out);
}

// Round 14
// 454.169 us; speedup vs baseline: 1.2987x; 1.2987x over previous
//
#include <hip/hip_runtime.h>
#include <hip/hip_fp16.h>

#define N_NODES 100000
#define E_EDGES 1600000
#define F 256              // feature width at every stage
#define LV_OFF 12800000    // 100000*128
#define NBUK 782           // ceil(100000/128) dst-buckets of 128 nodes
#define EPB 8192           // edges per binning block
#define NBLK_BIN 196       // ceil(1.6M/8192)

typedef _Float16 half8 __attribute__((ext_vector_type(8)));
typedef _Float16 f16x4 __attribute__((ext_vector_type(4)));
typedef float    f32x4 __attribute__((ext_vector_type(4)));
typedef unsigned u32x4 __attribute__((ext_vector_type(4)));

// fp16-pair (packed in u32) fused into two fp32 accumulators via v_fma_mix_f32.
// Bit-identical to cvt_f32_f16 + v_add_f32 (product with 1.0 is exact, fp32 add).
__device__ __forceinline__ void fmix2(float& lo, float& hi, unsigned v) {
    asm("v_fma_mix_f32 %0, %2, 1.0, %0 op_sel_hi:[1,0,0]\n\t"
        "v_fma_mix_f32 %1, %2, 1.0, %1 op_sel:[1,0,0] op_sel_hi:[1,0,0]"
        : "+v"(lo), "+v"(hi) : "v"(v));
}

__device__ __forceinline__ void acc_row(float* a, half8 v) {
    u32x4 u = __builtin_bit_cast(u32x4, v);
    fmix2(a[0], a[1], u[0]);
    fmix2(a[2], a[3], u[1]);
    fmix2(a[4], a[5], u[2]);
    fmix2(a[6], a[7], u[3]);
}

// ---------------- fused prep: wprep (256 blocks) + binA-with-count (196 blocks) ----------------
__global__ __launch_bounds__(256) void k_prep(
    const float* __restrict__ W1, const float* __restrict__ Wmu, const float* __restrict__ Wlv,
    _Float16* __restrict__ Wt1, _Float16* __restrict__ Wtc,
    const int* __restrict__ dst, int* __restrict__ gcnt, int* __restrict__ cbase,
    int* __restrict__ cnt)
{
    __shared__ int h[NBUK];
    int bid = blockIdx.x, tid = threadIdx.x;
    if (bid < 256) {
        int idx = bid * 256 + tid;   // 65536
        int n = idx >> 8, k = idx & 255;
        Wt1[n * 256 + k] = (_Float16)W1[k * 256 + n];
        float wc = (n < 128) ? Wmu[k * 128 + n] : Wlv[k * 128 + (n - 128)];
        Wtc[n * 256 + k] = (_Float16)wc;
        return;
    }
    int blk = bid - 256;             // 0..195
    for (int b = tid; b < NBUK; b += 256) h[b] = 0;
    __syncthreads();
    int e0 = blk * EPB, e1 = min(e0 + EPB, E_EDGES);
    for (int e = e0 + tid; e < e1; e += 256) {
        int d = dst[e];
        atomicAdd(&h[d >> 7], 1);    // bucket histogram (LDS)
        atomicAdd(&cnt[d], 1);       // per-node degree (global)
    }
    __syncthreads();
    for (int b = tid; b < NBUK; b += 256) {
        int c = h[b];
        cbase[blk * NBUK + b] = c ? atomicAdd(&gcnt[b], c) : 0;
    }
}

// ---------------- fused: bucket scan (block 0) + dis (blocks 1..98) ----------------
__global__ __launch_bounds__(1024) void k_scan_dis(const int* __restrict__ gcnt,
                                                   int* __restrict__ gbase,
                                                   const int* __restrict__ cnt,
                                                   float* __restrict__ dis) {
    int tid = threadIdx.x;
    if (blockIdx.x != 0) {
        int i = (blockIdx.x - 1) * 1024 + tid;
        if (i < N_NODES) dis[i] = rsqrtf((float)cnt[i] + 1.0f);
        return;
    }
    __shared__ int sd[1024];
    int v = (tid < NBUK) ? gcnt[tid] : 0;
    sd[tid] = v;
    __syncthreads();
    for (int off = 1; off < 1024; off <<= 1) {
        int t = (tid >= off) ? sd[tid - off] : 0;
        __syncthreads();
        sd[tid] += t;
        __syncthreads();
    }
    if (tid < NBUK) gbase[tid] = sd[tid] - v;    // exclusive
    if (tid == NBUK - 1) gbase[NBUK] = sd[tid];  // total = E
}

// ---------------- fp16 MFMA GEMM tile body, 8 waves, 64x64 per wave, epilogue *dis[m] ----------------
// A [M,256] row-major (fp32 or fp16, NT loads: read-once); Bt fp16 [256n][256k]; G fp16 [M,256].
template <typename TA>
__device__ __forceinline__ void gemm_tile(
    const TA* __restrict__ A, const _Float16* __restrict__ Bt,
    const float* __restrict__ dis, _Float16* __restrict__ G, int M,
    int m0, int tid, _Float16* Ah, _Float16* Bh)
{
    const int wave = tid >> 6, lane = tid & 63;
    const int wm   = wave & 1, wn = wave >> 1;      // 64-row half, 64-col quarter
    const int lrow = lane & 15, kgrp = lane >> 4;

    f32x4 acc[4][4];
#pragma unroll
    for (int i = 0; i < 4; i++)
#pragma unroll
        for (int j = 0; j < 4; j++) acc[i][j] = (f32x4){0.f, 0.f, 0.f, 0.f};

    for (int kt = 0; kt < 256; kt += 64) {
        // ---- stage A (512 threads) ----
        if constexpr (sizeof(TA) == 4) {
#pragma unroll
            for (int p = 0; p < 4; ++p) {
                int u = p * 512 + tid;        // 2048 float4
                int row = u >> 4, kq = u & 15;
                int gm = m0 + row; if (gm >= M) gm = M - 1;
                f32x4 v = __builtin_nontemporal_load(
                    reinterpret_cast<const f32x4*>((const float*)A + (size_t)gm * F + kt + kq * 4));
                f16x4 h4;
                h4[0] = (_Float16)v[0]; h4[1] = (_Float16)v[1];
                h4[2] = (_Float16)v[2]; h4[3] = (_Float16)v[3];
                *reinterpret_cast<f16x4*>(&Ah[row * 64 + ((kq * 4) ^ ((row & 7) << 3))]) = h4;
            }
        } else {
#pragma unroll
            for (int p = 0; p < 2; ++p) {
                int u = p * 512 + tid;        // 1024 half8
                int row = u >> 3, slot = u & 7;
                int gm = m0 + row; if (gm >= M) gm = M - 1;
                half8 v = __builtin_nontemporal_load(
                    reinterpret_cast<const half8*>((const _Float16*)A + (size_t)gm * F + kt + slot * 8));
                *reinterpret_cast<half8*>(&Ah[row * 64 + ((slot * 8) ^ ((row & 7) << 3))]) = v;
            }
        }
        // ---- stage B (full 256 cols; L2-hot, reused by all blocks) ----
#pragma unroll
        for (int p = 0; p < 4; ++p) {
            int u = p * 512 + tid;            // 2048 half8
            int n = u >> 3, slot = u & 7;
            half8 v = *reinterpret_cast<const half8*>(Bt + (size_t)n * F + kt + slot * 8);
            *reinterpret_cast<half8*>(&Bh[n * 64 + ((slot * 8) ^ ((n & 7) << 3))]) = v;
        }
        __syncthreads();
        // ---- compute: 2 k-substeps of 32 ----
#pragma unroll
        for (int ks = 0; ks < 2; ++ks) {
            int kk = ks * 32 + kgrp * 8;
            half8 ah[4];
#pragma unroll
            for (int i = 0; i < 4; ++i) {
                int row = wm * 64 + i * 16 + lrow;
                ah[i] = *reinterpret_cast<const half8*>(&Ah[row * 64 + (kk ^ ((row & 7) << 3))]);
            }
#pragma unroll
            for (int j = 0; j < 4; ++j) {
                int col = wn * 64 + j * 16 + lrow;
                half8 bh = *reinterpret_cast<const half8*>(&Bh[col * 64 + (kk ^ ((col & 7) << 3))]);
#pragma unroll
                for (int i = 0; i < 4; ++i)
                    acc[i][j] = __builtin_amdgcn_mfma_f32_16x16x32_f16(ah[i], bh, acc[i][j], 0, 0, 0);
            }
        }
        __syncthreads();
    }

    // ---- epilogue: C row = kgrp*4 + r, col = lrow; scale by dis[m] ----
#pragma unroll
    for (int i = 0; i < 4; ++i) {
#pragma unroll
        for (int r = 0; r < 4; ++r) {
            int m = m0 + wm * 64 + i * 16 + kgrp * 4 + r;
            if (m >= M) continue;
            float dv = dis[m];
#pragma unroll
            for (int j = 0; j < 4; ++j) {
                int n = wn * 64 + j * 16 + lrow;
                G[(size_t)m * F + n] = (_Float16)(acc[i][j][r] * dv);
            }
        }
    }
}

// ---------------- fused: GEMM-1 (782 tiles) + binC (196 blocks), interleaved 4:1 ----------------
__global__ __launch_bounds__(512, 4) void k_gemm_binC(
    const float* __restrict__ A, const _Float16* __restrict__ Bt,
    const float* __restrict__ dis, _Float16* __restrict__ G, int M,
    const int* __restrict__ src, const int* __restrict__ dst,
    const int* __restrict__ gbase, const int* __restrict__ cbase,
    unsigned long long* __restrict__ ebuf)
{
    __shared__ _Float16 smem[128 * 64 + 256 * 64];   // 48 KB, reused by both roles
    int bid = blockIdx.x, tid = threadIdx.x;
    int r5 = bid % 5;
    if (r5 < 4) {
        int gid = (bid / 5) * 4 + r5;
        if (gid < 782)
            gemm_tile<float>(A, Bt, dis, G, M, gid * 128, tid, smem, smem + 128 * 64);
        return;
    }
    // ---- binC role ----
    int* h2 = (int*)smem;          // [NBUK]
    int* bs = h2 + NBUK;           // [NBUK]
    int blk = bid / 5;             // 0..195
    for (int b = tid; b < NBUK; b += 512) {
        h2[b] = 0;
        bs[b] = gbase[b] + cbase[blk * NBUK + b];
    }
    __syncthreads();
    int e0 = blk * EPB, e1 = min(e0 + EPB, E_EDGES);
    for (int e = e0 + tid; e < e1; e += 512) {
        int d = dst[e];
        int b = d >> 7;
        int lr = atomicAdd(&h2[b], 1);
        ebuf[bs[b] + lr] = ((unsigned long long)(unsigned)d << 32) | (unsigned)src[e];
    }
}

// ---------------- standalone fp16 GEMM (layer 2) ----------------
__global__ __launch_bounds__(512, 4) void k_gemm_f16(
    const _Float16* __restrict__ A, const _Float16* __restrict__ Bt,
    const float* __restrict__ dis, _Float16* __restrict__ G, int M)
{
    __shared__ _Float16 smem[128 * 64 + 256 * 64];
    gemm_tile<_Float16>(A, Bt, dis, G, M, blockIdx.x * 128, threadIdx.x, smem, smem + 128 * 64);
}

// ---------------- fused binD + layer-1 aggregate: one block per bucket, 1024 threads ----------------
// Phase A: sort bucket's ebuf segment by dst-local -> csr_src (global, L2-hot) + row_off.
// Phase B: aggregate the bucket's 128 dst rows (16 waves x 8 rows), h -> fp16.
__global__ __launch_bounds__(1024, 8) void k_binDagg(
    const unsigned long long* __restrict__ ebuf, const int* __restrict__ gbase,
    int* __restrict__ csr_src, int* __restrict__ row_off,
    const _Float16* __restrict__ g1, const float* __restrict__ dis,
    const float* __restrict__ b1, _Float16* __restrict__ hout)
{
    __shared__ int dh[128], dsc[128], dcur[128];
    const int b = blockIdx.x, tid = threadIdx.x;
    const int s0 = gbase[b], s1 = gbase[b + 1];

    // ---- phase A: binD sort ----
    if (tid < 128) dh[tid] = 0;
    __syncthreads();
    for (int i = s0 + tid; i < s1; i += 1024)
        atomicAdd(&dh[(int)(ebuf[i] >> 32) & 127], 1);
    __syncthreads();
    if (tid < 128) dsc[tid] = dh[tid];
    __syncthreads();
    for (int off = 1; off < 128; off <<= 1) {
        int t = 0;
        if (tid < 128 && tid >= off) t = dsc[tid - off];
        __syncthreads();
        if (tid < 128) dsc[tid] += t;
        __syncthreads();
    }
    if (tid < 128) {
        int ex = dsc[tid] - dh[tid];   // exclusive within bucket
        dcur[tid] = ex;
        int node = b * 128 + tid;
        if (node < N_NODES) row_off[node] = s0 + ex;
    }
    if (b == 0 && tid == 128) row_off[N_NODES] = E_EDGES;
    __syncthreads();
    for (int i = s0 + tid; i < s1; i += 1024) {
        unsigned long long ed = ebuf[i];
        int dl = (int)(ed >> 32) & 127;
        int lr = atomicAdd(&dcur[dl], 1);
        csr_src[s0 + lr] = (int)(ed & 0xFFFFFFFFull);
    }
    __syncthreads();

    // ---- phase B: aggregate 8 rows per wave ----
    const int wave = tid >> 6, lane = tid & 63;
    const int hf = lane >> 5, lp = lane & 31;
    const half8* g8 = reinterpret_cast<const half8*>(g1);
    for (int it = 0; it < 8; ++it) {
        int r  = wave * 8 + it;            // 0..127
        int gr = b * 128 + r;
        if (gr >= N_NODES) break;
        float a0[8] = {0,0,0,0,0,0,0,0}, a1[8] = {0,0,0,0,0,0,0,0};
        if (hf == 0) {
            half8 sv = g8[(size_t)gr * 32 + lp];   // self-loop (g1 already dis-scaled)
#pragma unroll
            for (int k = 0; k < 8; k++) a0[k] = (float)sv[k];
        }
        int j0 = s0 + (dsc[r] - dh[r]), j1 = s0 + dsc[r];
        int j = j0 + hf;
        for (; j + 10 < j1; j += 12) {
            int e0i = csr_src[j],     e1i = csr_src[j + 2], e2i = csr_src[j + 4];
            int e3i = csr_src[j + 6], e4i = csr_src[j + 8], e5i = csr_src[j + 10];
            half8 v0 = g8[(size_t)e0i * 32 + lp];
            half8 v1 = g8[(size_t)e1i * 32 + lp];
            half8 v2 = g8[(size_t)e2i * 32 + lp];
            half8 v3 = g8[(size_t)e3i * 32 + lp];
            half8 v4 = g8[(size_t)e4i * 32 + lp];
            half8 v5 = g8[(size_t)e5i * 32 + lp];
            acc_row(a0, v0); acc_row(a1, v1);
            acc_row(a0, v2); acc_row(a1, v3);
            acc_row(a0, v4); acc_row(a1, v5);
        }
        for (; j + 2 < j1; j += 4) {
            int eA = csr_src[j], eB = csr_src[j + 2];
            half8 vA = g8[(size_t)eA * 32 + lp];
            half8 vB = g8[(size_t)eB * 32 + lp];
            acc_row(a0, vA); acc_row(a1, vB);
        }
        if (j < j1) {
            int eA = csr_src[j];
            half8 vA = g8[(size_t)eA * 32 + lp];
            acc_row(a0, vA);
        }
#pragma unroll
        for (int k = 0; k < 8; k++) {
            a0[k] += a1[k];
            a0[k] += __shfl_xor(a0[k], 32);
        }
        float dd = dis[gr];
        int c = lp * 8 + hf * 4;
        float4 bb = *reinterpret_cast<const float4*>(b1 + c);
        f16x4 o;
        o[0] = (_Float16)fmaxf(fmaf(dd, a0[hf * 4 + 0], bb.x), 0.0f);
        o[1] = (_Float16)fmaxf(fmaf(dd, a0[hf * 4 + 1], bb.y), 0.0f);
        o[2] = (_Float16)fmaxf(fmaf(dd, a0[hf * 4 + 2], bb.z), 0.0f);
        o[3] = (_Float16)fmaxf(fmaf(dd, a0[hf * 4 + 3], bb.w), 0.0f);
        *reinterpret_cast<f16x4*>(hout + (size_t)gr * F + c) = o;
    }
}

// ---------------- CSR gather layer-2 epilogue (mu | logvar split) ----------------
__global__ __launch_bounds__(256) void k_aggregate_out(
    const _Float16* __restrict__ g, const int* __restrict__ row_off,
    const int* __restrict__ csr_src, const float* __restrict__ dis,
    const float* __restrict__ bmu, const float* __restrict__ blv,
    float* __restrict__ out)
{
    int d = blockIdx.x * 4 + (threadIdx.x >> 6);
    int lane = threadIdx.x & 63;
    int hf = lane >> 5, lp = lane & 31;
    const half8* g8 = reinterpret_cast<const half8*>(g);   // 32 half8 per row
    float a0[8] = {0,0,0,0,0,0,0,0}, a1[8] = {0,0,0,0,0,0,0,0};
    if (hf == 0) {
        half8 sv = g8[(size_t)d * 32 + lp];   // self-loop (g already dis-scaled)
#pragma unroll
        for (int k = 0; k < 8; k++) a0[k] = (float)sv[k];
    }
    int j0 = row_off[d], j1 = row_off[d + 1];
    int j = j0 + hf;
    for (; j + 10 < j1; j += 12) {
        int s0 = csr_src[j],     s1 = csr_src[j + 2], s2 = csr_src[j + 4];
        int s3 = csr_src[j + 6], s4 = csr_src[j + 8], s5 = csr_src[j + 10];
        half8 v0 = g8[(size_t)s0 * 32 + lp];
        half8 v1 = g8[(size_t)s1 * 32 + lp];
        half8 v2 = g8[(size_t)s2 * 32 + lp];
        half8 v3 = g8[(size_t)s3 * 32 + lp];
        half8 v4 = g8[(size_t)s4 * 32 + lp];
        half8 v5 = g8[(size_t)s5 * 32 + lp];
        acc_row(a0, v0); acc_row(a1, v1);
        acc_row(a0, v2); acc_row(a1, v3);
        acc_row(a0, v4); acc_row(a1, v5);
    }
    for (; j + 2 < j1; j += 4) {
        int sA = csr_src[j], sB = csr_src[j + 2];
        half8 vA = g8[(size_t)sA * 32 + lp];
        half8 vB = g8[(size_t)sB * 32 + lp];
        acc_row(a0, vA); acc_row(a1, vB);
    }
    if (j < j1) {
        int sA = csr_src[j];
        half8 vA = g8[(size_t)sA * 32 + lp];
        acc_row(a0, vA);
    }
#pragma unroll
    for (int k = 0; k < 8; k++) {
        a0[k] += a1[k];
        a0[k] += __shfl_xor(a0[k], 32);
    }
    float dd = dis[d];
    int ch = lp * 8 + hf * 4;                 // 0..252
    float va = a0[hf * 4 + 0], vb = a0[hf * 4 + 1], vc = a0[hf * 4 + 2], vd = a0[hf * 4 + 3];
    if (ch < 128) {
        float4 bb = *reinterpret_cast<const float4*>(bmu + ch);
        f32x4 o = {fmaf(dd, va, bb.x), fmaf(dd, vb, bb.y),
                   fmaf(dd, vc, bb.z), fmaf(dd, vd, bb.w)};
        __builtin_nontemporal_store(o, reinterpret_cast<f32x4*>(out + (size_t)d * 128 + ch));
    } else {
        int c2 = ch - 128;
        float4 bb = *reinterpret_cast<const float4*>(blv + c2);
        f32x4 o = {fmaf(dd, va, bb.x), fmaf(dd, vb, bb.y),
                   fmaf(dd, vc, bb.z), fmaf(dd, vd, bb.w)};
        __builtin_nontemporal_store(o, reinterpret_cast<f32x4*>(out + LV_OFF + (size_t)d * 128 + c2));
    }
}

extern "C" void kernel_launch(void* const* d_in, const int* in_sizes, int n_in,
                              void* d_out, int out_size, void* d_ws, size_t ws_size,
                              hipStream_t stream) {
    const float* x   = (const float*)d_in[0];
    const int*   ei  = (const int*)d_in[1];
    const int*   src = ei;
    const int*   dst = ei + E_EDGES;
    const float* W1  = (const float*)d_in[2];
    const float* b1  = (const float*)d_in[3];
    const float* Wmu = (const float*)d_in[4];
    const float* bmu = (const float*)d_in[5];
    const float* Wlv = (const float*)d_in[6];
    const float* blv = (const float*)d_in[7];
    float* out = (float*)d_out;

    // workspace carve-up (1 KiB aligned)
    char* ws = (char*)d_ws;
    size_t o = 0;
    auto carve = [&](size_t bytes) -> char* {
        char* p = ws + o;
        o = (o + bytes + 1023) & ~(size_t)1023;
        return p;
    };
    float*    dis     = (float*)   carve(400000);
    int*      cnt     = (int*)     carve(400000);
    int*      row_off = (int*)     carve(400004);
    int*      gcnt    = (int*)     carve(NBUK * 4);
    int*      gbase   = (int*)     carve((NBUK + 1) * 4);
    int*      cbase   = (int*)     carve((size_t)NBLK_BIN * NBUK * 4);   // 613 KB
    _Float16* Wt1     = (_Float16*)carve(131072);
    _Float16* Wtc     = (_Float16*)carve(131072);
    int*      csr_src = (int*)     carve((size_t)E_EDGES * 4);           // 6.4 MB
    unsigned long long* ebuf = (unsigned long long*)carve((size_t)E_EDGES * 8);  // 12.8 MB
    _Float16* g       = (_Float16*)carve((size_t)N_NODES * F * 2);       // 51.2 MB
    (void)ws_size;

    // h (fp16, 51.2 MB) lives in the upper half of d_out; dead before agg_out's lv writes land
    _Float16* h16 = (_Float16*)(out + LV_OFF);

    // ---- pipeline ----
    hipMemsetAsync(cnt, 0, 400000, stream);
    hipMemsetAsync(gcnt, 0, NBUK * 4, stream);
    k_prep    <<<256 + NBLK_BIN, 256, 0, stream>>>(W1, Wmu, Wlv, Wt1, Wtc, dst, gcnt, cbase, cnt);
    k_scan_dis<<<99, 1024, 0, stream>>>(gcnt, gbase, cnt, dis);
    // layer-1 GEMM (dis epilogue) fused with binC
    k_gemm_binC<<<980, 512, 0, stream>>>(x, Wt1, dis, g, N_NODES, src, dst, gbase, cbase, ebuf);
    // fused binD sort + layer-1 aggregate -> h (fp16)
    k_binDagg  <<<NBUK, 1024, 0, stream>>>(ebuf, gbase, csr_src, row_off, g, dis, b1, h16);
    // layer 2 (mu|lv fused)
    k_gemm_f16<<<782, 512, 0, stream>>>(h16, Wtc, dis, g, N_NODES);
    k_aggregate_out<<<N_NODES / 4, 256, 0, stream>>>(g, row_off, csr_src, dis, bmu, blv, out);
}

// Round 15
// 419.919 us; speedup vs baseline: 1.4047x; 1.0816x over previous
//
#include <hip/hip_runtime.h>
#include <hip/hip_fp16.h>

#define N_NODES 100000
#define E_EDGES 1600000
#define F 256              // feature width at every stage
#define LV_OFF 12800000    // 100000*128
#define NBUK 782           // ceil(100000/128) dst-buckets of 128 nodes
#define EPB 8192           // edges per binning block
#define NBLK_BIN 196       // ceil(1.6M/8192)

typedef _Float16 half8 __attribute__((ext_vector_type(8)));
typedef _Float16 f16x4 __attribute__((ext_vector_type(4)));
typedef float    f32x4 __attribute__((ext_vector_type(4)));
typedef unsigned u32x4 __attribute__((ext_vector_type(4)));

// fp16-pair (packed in u32) fused into two fp32 accumulators via v_fma_mix_f32.
// Bit-identical to cvt_f32_f16 + v_add_f32 (product with 1.0 is exact, fp32 add).
__device__ __forceinline__ void fmix2(float& lo, float& hi, unsigned v) {
    asm("v_fma_mix_f32 %0, %2, 1.0, %0 op_sel_hi:[1,0,0]\n\t"
        "v_fma_mix_f32 %1, %2, 1.0, %1 op_sel:[1,0,0] op_sel_hi:[1,0,0]"
        : "+v"(lo), "+v"(hi) : "v"(v));
}

__device__ __forceinline__ void acc_row(float* a, half8 v) {
    u32x4 u = __builtin_bit_cast(u32x4, v);
    fmix2(a[0], a[1], u[0]);
    fmix2(a[2], a[3], u[1]);
    fmix2(a[4], a[5], u[2]);
    fmix2(a[6], a[7], u[3]);
}

// async global->LDS, 16B per lane; LDS dest = uniform base + lane*16
__device__ __forceinline__ void gload_lds16(const void* gsrc, void* ldst) {
    __builtin_amdgcn_global_load_lds(
        (const __attribute__((address_space(1))) void*)gsrc,
        (__attribute__((address_space(3))) void*)ldst, 16, 0, 0);
}

// ---------------- fused prep: wprep (256 blocks, PRE-SWIZZLED) + binA-with-count (196) ----------------
__global__ __launch_bounds__(256) void k_prep(
    const float* __restrict__ W1, const float* __restrict__ Wmu, const float* __restrict__ Wlv,
    _Float16* __restrict__ Wt1, _Float16* __restrict__ Wtc,
    const int* __restrict__ dst, int* __restrict__ gcnt, int* __restrict__ cbase,
    int* __restrict__ cnt)
{
    __shared__ int h[NBUK];
    int bid = blockIdx.x, tid = threadIdx.x;
    if (bid < 256) {
        int idx = bid * 256 + tid;   // 65536
        int n = idx >> 8, k = idx & 255;
        // pre-swizzle so linear global_load_lds yields the XOR-swizzled LDS layout
        int ksw = (k & 192) | (((((k >> 3) & 7) ^ (n & 7))) << 3) | (k & 7);
        Wt1[n * 256 + ksw] = (_Float16)W1[k * 256 + n];
        float wc = (n < 128) ? Wmu[k * 128 + n] : Wlv[k * 128 + (n - 128)];
        Wtc[n * 256 + ksw] = (_Float16)wc;
        return;
    }
    int blk = bid - 256;             // 0..195
    for (int b = tid; b < NBUK; b += 256) h[b] = 0;
    __syncthreads();
    int e0 = blk * EPB, e1 = min(e0 + EPB, E_EDGES);
    for (int e = e0 + tid; e < e1; e += 256) {
        int d = dst[e];
        atomicAdd(&h[d >> 7], 1);    // bucket histogram (LDS)
        atomicAdd(&cnt[d], 1);       // per-node degree (global)
    }
    __syncthreads();
    for (int b = tid; b < NBUK; b += 256) {
        int c = h[b];
        cbase[blk * NBUK + b] = c ? atomicAdd(&gcnt[b], c) : 0;
    }
}

// ---------------- fused: bucket scan (block 0) + dis (blocks 1..98) ----------------
__global__ __launch_bounds__(1024) void k_scan_dis(const int* __restrict__ gcnt,
                                                   int* __restrict__ gbase,
                                                   const int* __restrict__ cnt,
                                                   float* __restrict__ dis) {
    int tid = threadIdx.x;
    if (blockIdx.x != 0) {
        int i = (blockIdx.x - 1) * 1024 + tid;
        if (i < N_NODES) dis[i] = rsqrtf((float)cnt[i] + 1.0f);
        return;
    }
    __shared__ int sd[1024];
    int v = (tid < NBUK) ? gcnt[tid] : 0;
    sd[tid] = v;
    __syncthreads();
    for (int off = 1; off < 1024; off <<= 1) {
        int t = (tid >= off) ? sd[tid - off] : 0;
        __syncthreads();
        sd[tid] += t;
        __syncthreads();
    }
    if (tid < NBUK) gbase[tid] = sd[tid] - v;    // exclusive
    if (tid == NBUK - 1) gbase[NBUK] = sd[tid];  // total = E
}

// ---------------- binning pass D: per-bucket group-by-dst -> csr_src, row_off ----------------
__global__ __launch_bounds__(256) void k_binD(const unsigned long long* __restrict__ ebuf,
                                              const int* __restrict__ gbase,
                                              int* __restrict__ csr_src, int* __restrict__ row_off) {
    __shared__ int dh[128], dsc[128], dcur[128];
    int b = blockIdx.x, tid = threadIdx.x;
    if (tid < 128) dh[tid] = 0;
    __syncthreads();
    int s0 = gbase[b], s1 = gbase[b + 1];
    for (int i = s0 + tid; i < s1; i += 256)
        atomicAdd(&dh[(int)(ebuf[i] >> 32) & 127], 1);
    __syncthreads();
    if (tid < 128) dsc[tid] = dh[tid];
    __syncthreads();
    for (int off = 1; off < 128; off <<= 1) {
        int t = 0;
        if (tid < 128 && tid >= off) t = dsc[tid - off];
        __syncthreads();
        if (tid < 128) dsc[tid] += t;
        __syncthreads();
    }
    if (tid < 128) {
        int ex = dsc[tid] - dh[tid];   // exclusive within bucket
        dcur[tid] = ex;
        int node = b * 128 + tid;
        if (node < N_NODES) row_off[node] = s0 + ex;
    }
    if (b == 0 && tid == 128) row_off[N_NODES] = E_EDGES;
    __syncthreads();
    for (int i = s0 + tid; i < s1; i += 256) {
        unsigned long long ed = ebuf[i];
        int dl = (int)(ed >> 32) & 127;
        int lr = atomicAdd(&dcur[dl], 1);
        csr_src[s0 + lr] = (int)(ed & 0xFFFFFFFFull);
    }
}

// ---------------- fp16 MFMA GEMM tile body, 8 waves, 64x64 per wave, epilogue *dis[m] ----------------
// A [M,256] row-major: fp32 (VGPR staging) or fp16 PRE-SWIZZLED (global_load_lds staging).
// Bt fp16 [256n][256k] PRE-SWIZZLED; G fp16 [M,256] normal layout.
template <typename TA>
__device__ __forceinline__ void gemm_tile(
    const TA* __restrict__ A, const _Float16* __restrict__ Bt,
    const float* __restrict__ dis, _Float16* __restrict__ G, int M,
    int m0, int tid, _Float16* Ah, _Float16* Bh)
{
    const int wave = tid >> 6, lane = tid & 63;
    const int wm   = wave & 1, wn = wave >> 1;      // 64-row half, 64-col quarter
    const int lrow = lane & 15, kgrp = lane >> 4;

    f32x4 acc[4][4];
#pragma unroll
    for (int i = 0; i < 4; i++)
#pragma unroll
        for (int j = 0; j < 4; j++) acc[i][j] = (f32x4){0.f, 0.f, 0.f, 0.f};

    for (int kt = 0; kt < 256; kt += 64) {
        // ---- stage A ----
        if constexpr (sizeof(TA) == 4) {
            // fp32 -> fp16 convert via VGPRs, swizzled ds_write
#pragma unroll
            for (int p = 0; p < 4; ++p) {
                int u = p * 512 + tid;        // 2048 float4
                int row = u >> 4, kq = u & 15;
                int gm = m0 + row; if (gm >= M) gm = M - 1;
                f32x4 v = __builtin_nontemporal_load(
                    reinterpret_cast<const f32x4*>((const float*)A + (size_t)gm * F + kt + kq * 4));
                f16x4 h4;
                h4[0] = (_Float16)v[0]; h4[1] = (_Float16)v[1];
                h4[2] = (_Float16)v[2]; h4[3] = (_Float16)v[3];
                *reinterpret_cast<f16x4*>(&Ah[row * 64 + ((kq * 4) ^ ((row & 7) << 3))]) = h4;
            }
        } else {
            // pre-swizzled fp16 source: pure async copy, linear LDS
#pragma unroll
            for (int p = 0; p < 2; ++p) {
                int q = wave * 2 + p;             // 0..15
                int u = q * 64 + lane;            // 16B unit, 0..1023
                int row = u >> 3, slot = u & 7;
                int gm = m0 + row; if (gm >= M) gm = M - 1;
                gload_lds16((const _Float16*)A + (size_t)gm * F + kt + slot * 8,
                            Ah + (size_t)q * 512);
            }
        }
        // ---- stage B: pre-swizzled, async copy, linear LDS ----
#pragma unroll
        for (int p = 0; p < 4; ++p) {
            int q = wave * 4 + p;                 // 0..31
            int u = q * 64 + lane;                // 16B unit, 0..2047
            int n = u >> 3, slot = u & 7;
            gload_lds16(Bt + (size_t)n * F + kt + slot * 8,
                        Bh + (size_t)q * 512);
        }
        __syncthreads();
        // ---- compute: 2 k-substeps of 32 ----
#pragma unroll
        for (int ks = 0; ks < 2; ++ks) {
            int kk = ks * 32 + kgrp * 8;
            half8 ah[4];
#pragma unroll
            for (int i = 0; i < 4; ++i) {
                int row = wm * 64 + i * 16 + lrow;
                ah[i] = *reinterpret_cast<const half8*>(&Ah[row * 64 + (kk ^ ((row & 7) << 3))]);
            }
#pragma unroll
            for (int j = 0; j < 4; ++j) {
                int col = wn * 64 + j * 16 + lrow;
                half8 bh = *reinterpret_cast<const half8*>(&Bh[col * 64 + (kk ^ ((col & 7) << 3))]);
#pragma unroll
                for (int i = 0; i < 4; ++i)
                    acc[i][j] = __builtin_amdgcn_mfma_f32_16x16x32_f16(ah[i], bh, acc[i][j], 0, 0, 0);
            }
        }
        __syncthreads();
    }

    // ---- epilogue: C row = kgrp*4 + r, col = lrow; scale by dis[m] ----
#pragma unroll
    for (int i = 0; i < 4; ++i) {
#pragma unroll
        for (int r = 0; r < 4; ++r) {
            int m = m0 + wm * 64 + i * 16 + kgrp * 4 + r;
            if (m >= M) continue;
            float dv = dis[m];
#pragma unroll
            for (int j = 0; j < 4; ++j) {
                int n = wn * 64 + j * 16 + lrow;
                G[(size_t)m * F + n] = (_Float16)(acc[i][j][r] * dv);
            }
        }
    }
}

// ---------------- fused: GEMM-1 (782 tiles) + binC (196 blocks), interleaved 4:1 ----------------
__global__ __launch_bounds__(512, 4) void k_gemm_binC(
    const float* __restrict__ A, const _Float16* __restrict__ Bt,
    const float* __restrict__ dis, _Float16* __restrict__ G, int M,
    const int* __restrict__ src, const int* __restrict__ dst,
    const int* __restrict__ gbase, const int* __restrict__ cbase,
    unsigned long long* __restrict__ ebuf)
{
    __shared__ _Float16 smem[128 * 64 + 256 * 64];   // 48 KB, reused by both roles
    int bid = blockIdx.x, tid = threadIdx.x;
    int r5 = bid % 5;
    if (r5 < 4) {
        int gid = (bid / 5) * 4 + r5;
        if (gid < 782)
            gemm_tile<float>(A, Bt, dis, G, M, gid * 128, tid, smem, smem + 128 * 64);
        return;
    }
    // ---- binC role ----
    int* h2 = (int*)smem;          // [NBUK]
    int* bs = h2 + NBUK;           // [NBUK]
    int blk = bid / 5;             // 0..195
    for (int b = tid; b < NBUK; b += 512) {
        h2[b] = 0;
        bs[b] = gbase[b] + cbase[blk * NBUK + b];
    }
    __syncthreads();
    int e0 = blk * EPB, e1 = min(e0 + EPB, E_EDGES);
    for (int e = e0 + tid; e < e1; e += 512) {
        int d = dst[e];
        int b = d >> 7;
        int lr = atomicAdd(&h2[b], 1);
        ebuf[bs[b] + lr] = ((unsigned long long)(unsigned)d << 32) | (unsigned)src[e];
    }
}

// ---------------- standalone fp16 GEMM (layer 2); A = pre-swizzled h ----------------
__global__ __launch_bounds__(512, 4) void k_gemm_f16(
    const _Float16* __restrict__ A, const _Float16* __restrict__ Bt,
    const float* __restrict__ dis, _Float16* __restrict__ G, int M)
{
    __shared__ _Float16 smem[128 * 64 + 256 * 64];
    gemm_tile<_Float16>(A, Bt, dis, G, M, blockIdx.x * 128, threadIdx.x, smem, smem + 128 * 64);
}

// ---------------- CSR gather: half-wave per row, 6-deep pipeline, fma_mix accumulate ----------------
// RELU=1: writes h PRE-SWIZZLED fp16 (consumed by gemm_f16's global_load_lds staging).
template <int RELU>
__device__ __forceinline__ void aggregate_body(
    const _Float16* __restrict__ g, const int* __restrict__ row_off,
    const int* __restrict__ csr_src, const float* __restrict__ dis,
    const float* __restrict__ bmu, const float* __restrict__ blv,
    _Float16* __restrict__ hout, float* __restrict__ out)
{
    int d = blockIdx.x * 4 + (threadIdx.x >> 6);
    int lane = threadIdx.x & 63;
    int hf = lane >> 5, lp = lane & 31;
    const half8* g8 = reinterpret_cast<const half8*>(g);   // 32 half8 per row
    float a0[8] = {0,0,0,0,0,0,0,0}, a1[8] = {0,0,0,0,0,0,0,0};
    if (hf == 0) {
        half8 sv = g8[(size_t)d * 32 + lp];   // self-loop (g already dis-scaled)
#pragma unroll
        for (int k = 0; k < 8; k++) a0[k] = (float)sv[k];
    }
    int j0 = row_off[d], j1 = row_off[d + 1];
    int j = j0 + hf;
    // 6-deep main: 12 edges per wave-iteration across both halves
    for (; j + 10 < j1; j += 12) {
        int s0 = csr_src[j],     s1 = csr_src[j + 2], s2 = csr_src[j + 4];
        int s3 = csr_src[j + 6], s4 = csr_src[j + 8], s5 = csr_src[j + 10];
        half8 v0 = g8[(size_t)s0 * 32 + lp];
        half8 v1 = g8[(size_t)s1 * 32 + lp];
        half8 v2 = g8[(size_t)s2 * 32 + lp];
        half8 v3 = g8[(size_t)s3 * 32 + lp];
        half8 v4 = g8[(size_t)s4 * 32 + lp];
        half8 v5 = g8[(size_t)s5 * 32 + lp];
        acc_row(a0, v0); acc_row(a1, v1);
        acc_row(a0, v2); acc_row(a1, v3);
        acc_row(a0, v4); acc_row(a1, v5);
    }
    for (; j + 2 < j1; j += 4) {
        int sA = csr_src[j], sB = csr_src[j + 2];
        half8 vA = g8[(size_t)sA * 32 + lp];
        half8 vB = g8[(size_t)sB * 32 + lp];
        acc_row(a0, vA); acc_row(a1, vB);
    }
    if (j < j1) {
        int sA = csr_src[j];
        half8 vA = g8[(size_t)sA * 32 + lp];
        acc_row(a0, vA);
    }
#pragma unroll
    for (int k = 0; k < 8; k++) {
        a0[k] += a1[k];
        a0[k] += __shfl_xor(a0[k], 32);
    }
    float dd = dis[d];
    if (RELU) {
        int c = lp * 8 + hf * 4;              // logical channel
        float4 bb = *reinterpret_cast<const float4*>(bmu + c);
        f16x4 o;
        o[0] = (_Float16)fmaxf(fmaf(dd, a0[hf * 4 + 0], bb.x), 0.0f);
        o[1] = (_Float16)fmaxf(fmaf(dd, a0[hf * 4 + 1], bb.y), 0.0f);
        o[2] = (_Float16)fmaxf(fmaf(dd, a0[hf * 4 + 2], bb.z), 0.0f);
        o[3] = (_Float16)fmaxf(fmaf(dd, a0[hf * 4 + 3], bb.w), 0.0f);
        // pre-swizzled store: chunk=lp>>3, slot=(lp&7)^(row&7), off=hf*4
        int csw = ((lp >> 3) << 6) | ((((lp & 7) ^ (d & 7))) << 3) | (hf * 4);
        *reinterpret_cast<f16x4*>(hout + (size_t)d * F + csw) = o;
    } else {
        int ch = lp * 8 + hf * 4;                 // 0..252
        float va = a0[hf * 4 + 0], vb = a0[hf * 4 + 1], vc = a0[hf * 4 + 2], vd = a0[hf * 4 + 3];
        if (ch < 128) {
            float4 bb = *reinterpret_cast<const float4*>(bmu + ch);
            f32x4 o = {fmaf(dd, va, bb.x), fmaf(dd, vb, bb.y),
                       fmaf(dd, vc, bb.z), fmaf(dd, vd, bb.w)};
            __builtin_nontemporal_store(o, reinterpret_cast<f32x4*>(out + (size_t)d * 128 + ch));
        } else {
            int c2 = ch - 128;
            float4 bb = *reinterpret_cast<const float4*>(blv + c2);
            f32x4 o = {fmaf(dd, va, bb.x), fmaf(dd, vb, bb.y),
                       fmaf(dd, vc, bb.z), fmaf(dd, vd, bb.w)};
            __builtin_nontemporal_store(o, reinterpret_cast<f32x4*>(out + LV_OFF + (size_t)d * 128 + c2));
        }
    }
}

__global__ __launch_bounds__(256) void k_aggregate_relu(
    const _Float16* __restrict__ g, const int* __restrict__ row_off,
    const int* __restrict__ csr_src, const float* __restrict__ dis,
    const float* __restrict__ b, _Float16* __restrict__ h)
{
    aggregate_body<1>(g, row_off, csr_src, dis, b, nullptr, h, nullptr);
}

__global__ __launch_bounds__(256) void k_aggregate_out(
    const _Float16* __restrict__ g, const int* __restrict__ row_off,
    const int* __restrict__ csr_src, const float* __restrict__ dis,
    const float* __restrict__ bmu, const float* __restrict__ blv,
    float* __restrict__ out)
{
    aggregate_body<0>(g, row_off, csr_src, dis, bmu, blv, nullptr, out);
}

extern "C" void kernel_launch(void* const* d_in, const int* in_sizes, int n_in,
                              void* d_out, int out_size, void* d_ws, size_t ws_size,
                              hipStream_t stream) {
    const float* x   = (const float*)d_in[0];
    const int*   ei  = (const int*)d_in[1];
    const int*   src = ei;
    const int*   dst = ei + E_EDGES;
    const float* W1  = (const float*)d_in[2];
    const float* b1  = (const float*)d_in[3];
    const float* Wmu = (const float*)d_in[4];
    const float* bmu = (const float*)d_in[5];
    const float* Wlv = (const float*)d_in[6];
    const float* blv = (const float*)d_in[7];
    float* out = (float*)d_out;

    // workspace carve-up (1 KiB aligned)
    char* ws = (char*)d_ws;
    size_t o = 0;
    auto carve = [&](size_t bytes) -> char* {
        char* p = ws + o;
        o = (o + bytes + 1023) & ~(size_t)1023;
        return p;
    };
    float*    dis     = (float*)   carve(400000);
    int*      cnt     = (int*)     carve(400000);
    int*      row_off = (int*)     carve(400004);
    int*      gcnt    = (int*)     carve(NBUK * 4);
    int*      gbase   = (int*)     carve((NBUK + 1) * 4);
    int*      cbase   = (int*)     carve((size_t)NBLK_BIN * NBUK * 4);   // 613 KB
    _Float16* Wt1     = (_Float16*)carve(131072);
    _Float16* Wtc     = (_Float16*)carve(131072);
    int*      csr_src = (int*)     carve((size_t)E_EDGES * 4);           // 6.4 MB
    unsigned long long* ebuf = (unsigned long long*)carve((size_t)E_EDGES * 8);  // 12.8 MB
    _Float16* g       = (_Float16*)carve((size_t)N_NODES * F * 2);       // 51.2 MB
    (void)ws_size;

    // h (fp16, pre-swizzled, 51.2 MB) lives in the upper half of d_out;
    // dead before agg_out's lv writes land there.
    _Float16* h16 = (_Float16*)(out + LV_OFF);

    // ---- pipeline ----
    hipMemsetAsync(cnt, 0, 400000, stream);
    hipMemsetAsync(gcnt, 0, NBUK * 4, stream);
    k_prep    <<<256 + NBLK_BIN, 256, 0, stream>>>(W1, Wmu, Wlv, Wt1, Wtc, dst, gcnt, cbase, cnt);
    k_scan_dis<<<99, 1024, 0, stream>>>(gcnt, gbase, cnt, dis);
    // layer-1 GEMM (dis epilogue) fused with binC
    k_gemm_binC<<<980, 512, 0, stream>>>(x, Wt1, dis, g, N_NODES, src, dst, gbase, cbase, ebuf);
    k_binD     <<<NBUK, 256, 0, stream>>>(ebuf, gbase, csr_src, row_off);

    // layer 1 aggregate: h = fp16(relu(dis_d*(g[d]+sum g[s]) + b1)), pre-swizzled
    k_aggregate_relu<<<N_NODES / 4, 256, 0, stream>>>(g, row_off, csr_src, dis, b1, h16);

    // layer 2 (mu|lv fused)
    k_gemm_f16<<<782, 512, 0, stream>>>(h16, Wtc, dis, g, N_NODES);
    k_aggregate_out<<<N_NODES / 4, 256, 0, stream>>>(g, row_off, csr_src, dis, bmu, blv, out);
}